// Round 2
// baseline (36.097 us; speedup 1.0000x reference)
//
#include <hip/hip_runtime.h>
#include <hip/hip_bf16.h>

// WordPooling: hidden_states [B,S,H] fp32, segment_ids [B*S] sorted int32,
// output pooled [num_words, H] fp32 (mean over each contiguous word segment;
// empty words -> zeros).
//
// Two-kernel plan:
//   K1 (boundaries): token-parallel exact lower_bound table.
//       starts[w] = first token t with seg[t] >= w, for w in [0, W].
//       Token t owns all w in (seg[t-1], seg[t]]; virtual t==n owns (seg[n-1], W].
//       Removes the 30 serially-dependent binary-search loads per block that
//       round-1 profiling arithmetic identified as the latency gap.
//   K2 (pool): one block per word, two independent loads for [start,end),
//       then pure coalesced float4 streaming + mean.

__global__ __launch_bounds__(256)
void word_bounds_kernel(const int* __restrict__ seg,
                        int* __restrict__ starts,
                        int n_tokens, int n_words) {
    const int t = blockIdx.x * blockDim.x + threadIdx.x;
    if (t > n_tokens) return;
    const int prev = (t == 0) ? -1 : seg[t - 1];
    const int cur  = (t == n_tokens) ? n_words : seg[t];
    // starts[w] = t  for all w in (prev, cur]
    for (int w = prev + 1; w <= cur; ++w) {
        starts[w] = t;
    }
}

__global__ __launch_bounds__(256)
void word_pool_kernel(const float* __restrict__ hs,
                      const int* __restrict__ starts,
                      float* __restrict__ out,
                      int H) {
    const int w = blockIdx.x;
    const int start = starts[w];
    const int end   = starts[w + 1];

    const int h = threadIdx.x * 4;
    if (h >= H) return;

    float4 acc = make_float4(0.f, 0.f, 0.f, 0.f);
    for (int t = start; t < end; ++t) {
        const float4 v = *reinterpret_cast<const float4*>(&hs[(size_t)t * H + h]);
        acc.x += v.x; acc.y += v.y; acc.z += v.z; acc.w += v.w;
    }

    const int cnt = end - start;
    const float inv = (cnt > 0) ? (1.0f / (float)cnt) : 0.0f;
    acc.x *= inv; acc.y *= inv; acc.z *= inv; acc.w *= inv;

    *reinterpret_cast<float4*>(&out[(size_t)w * H + h]) = acc;
}

extern "C" void kernel_launch(void* const* d_in, const int* in_sizes, int n_in,
                              void* d_out, int out_size, void* d_ws, size_t ws_size,
                              hipStream_t stream) {
    const float* hs  = (const float*)d_in[0];   // [B*S, H] flattened
    const int*   seg = (const int*)d_in[1];     // [B*S], sorted
    float* out = (float*)d_out;

    const int n_tokens = in_sizes[1];              // B*S = 32768
    const int H        = in_sizes[0] / n_tokens;   // 1024
    const int n_words  = out_size / H;             // 8192

    int* starts = (int*)d_ws;                      // (n_words + 1) ints

    {
        const int total = n_tokens + 1;
        dim3 grid((total + 255) / 256), block(256);
        word_bounds_kernel<<<grid, block, 0, stream>>>(seg, starts, n_tokens, n_words);
    }
    {
        dim3 grid(n_words), block(256);
        word_pool_kernel<<<grid, block, 0, stream>>>(hs, starts, out, H);
    }
}

// Round 3
// 35.625 us; speedup vs baseline: 1.0132x; 1.0132x over previous
//
#include <hip/hip_runtime.h>
#include <hip/hip_bf16.h>

// WordPooling: hidden_states [B,S,H] fp32, segment_ids [B*S] sorted int32,
// output pooled [num_words, H] fp32 (mean per contiguous word segment;
// empty words -> zeros).
//
// Round-3 structure: ONE WAVE PER WORD (not one block per word).
//  - 4 waves/block, each wave handles word w = blockIdx.x*4 + waveId.
//  - Each lane owns 4 separated float4 column chunks (lane*4 + j*256 floats),
//    so each global_load_dwordx4 instruction is a contiguous 1 KB wave access
//    (perfect coalescing) AND each thread has 4 independent loads per row
//    (4x memory-level parallelism vs round 1/2).
//  - Binary search per wave: proven latency-hidden in rounds 1-2 (the K1
//    boundary-table variant was 1.1 us SLOWER due to the extra launch).

__device__ __forceinline__ int lower_bound_i32(const int* __restrict__ a, int n, int val) {
    int lo = 0, hi = n;
    while (lo < hi) {
        int mid = (lo + hi) >> 1;
        if (a[mid] < val) lo = mid + 1;
        else hi = mid;
    }
    return lo;
}

__global__ __launch_bounds__(256)
void word_pool_kernel(const float* __restrict__ hs,
                      const int* __restrict__ seg,
                      float* __restrict__ out,
                      int n_tokens, int H, int n_words) {
    const int wave = threadIdx.x >> 6;     // 0..3
    const int lane = threadIdx.x & 63;
    const int w = blockIdx.x * 4 + wave;
    if (w >= n_words) return;

    // Wave-uniform contiguous token range for this word.
    const int start = lower_bound_i32(seg, n_tokens, w);
    const int end   = lower_bound_i32(seg, n_tokens, w + 1);

    // H = 1024 = 64 lanes * 4 chunks * 4 floats.
    const int c0 = lane * 4;               // chunk j at column c0 + j*256

    float4 acc0 = make_float4(0.f, 0.f, 0.f, 0.f);
    float4 acc1 = acc0, acc2 = acc0, acc3 = acc0;

    for (int t = start; t < end; ++t) {
        const float* row = hs + (size_t)t * H + c0;
        const float4 v0 = *reinterpret_cast<const float4*>(row);
        const float4 v1 = *reinterpret_cast<const float4*>(row + 256);
        const float4 v2 = *reinterpret_cast<const float4*>(row + 512);
        const float4 v3 = *reinterpret_cast<const float4*>(row + 768);
        acc0.x += v0.x; acc0.y += v0.y; acc0.z += v0.z; acc0.w += v0.w;
        acc1.x += v1.x; acc1.y += v1.y; acc1.z += v1.z; acc1.w += v1.w;
        acc2.x += v2.x; acc2.y += v2.y; acc2.z += v2.z; acc2.w += v2.w;
        acc3.x += v3.x; acc3.y += v3.y; acc3.z += v3.z; acc3.w += v3.w;
    }

    const int cnt = end - start;
    const float inv = (cnt > 0) ? (1.0f / (float)cnt) : 0.0f;
    acc0.x *= inv; acc0.y *= inv; acc0.z *= inv; acc0.w *= inv;
    acc1.x *= inv; acc1.y *= inv; acc1.z *= inv; acc1.w *= inv;
    acc2.x *= inv; acc2.y *= inv; acc2.z *= inv; acc2.w *= inv;
    acc3.x *= inv; acc3.y *= inv; acc3.z *= inv; acc3.w *= inv;

    float* orow = out + (size_t)w * H + c0;
    *reinterpret_cast<float4*>(orow)       = acc0;
    *reinterpret_cast<float4*>(orow + 256) = acc1;
    *reinterpret_cast<float4*>(orow + 512) = acc2;
    *reinterpret_cast<float4*>(orow + 768) = acc3;
}

extern "C" void kernel_launch(void* const* d_in, const int* in_sizes, int n_in,
                              void* d_out, int out_size, void* d_ws, size_t ws_size,
                              hipStream_t stream) {
    const float* hs  = (const float*)d_in[0];   // [B*S, H] flattened
    const int*   seg = (const int*)d_in[1];     // [B*S], sorted
    float* out = (float*)d_out;

    const int n_tokens = in_sizes[1];              // B*S = 32768
    const int H        = in_sizes[0] / n_tokens;   // 1024
    const int n_words  = out_size / H;             // 8192

    dim3 grid((n_words + 3) / 4);
    dim3 block(256);
    word_pool_kernel<<<grid, block, 0, stream>>>(hs, seg, out, n_tokens, H, n_words);
}

// Round 4
// 34.701 us; speedup vs baseline: 1.0402x; 1.0266x over previous
//
#include <hip/hip_runtime.h>
#include <hip/hip_bf16.h>

// WordPooling: hidden_states [B,S,H] fp32, segment_ids [B*S] sorted int32,
// output pooled [num_words, H] fp32 (mean per contiguous word segment;
// empty words -> zeros).
//
// Round-4: wave-parallel lower_bound.
//  - r1-r3 showed the steady-state stream is BW-fed fine; the gap is the
//    kernel-start phase where ALL waves run 30 serially-dependent binary
//    search L2 loads (~3 us of dead HBM time).
//  - 64-way fan-out search: one scattered load per round, __ballot+popcount
//    narrows 32768 -> 512 -> 8 -> done. 3 dependent rounds per bound; the
//    two bounds (w, w+1) are independent chains and overlap in flight.

__device__ __forceinline__ int wave_lower_bound(const int* __restrict__ seg,
                                                int n, int val, int lane) {
    int lo = 0;
    int len = n;
    while (len > 64) {
        const int stride = (len + 63) >> 6;          // ceil(len/64)
        const int idx = lo + lane * stride;
        const int v = (idx < n) ? seg[idx] : 0x7fffffff;
        const unsigned long long m = __ballot(v < val);
        const int cnt = __popcll(m);                 // prefix count (seg sorted)
        if (cnt > 0) lo += (cnt - 1) * stride + 1;   // lb in (p[cnt-1], p[cnt]]
        len = stride;                                // window size after narrow
    }
    {
        // final round, stride 1; lanes beyond the window read seg[idx] >= val
        // (sorted), or are clamped to INT_MAX, so popcount == lb - lo exactly.
        const int idx = lo + lane;
        const int v = (idx < n) ? seg[idx] : 0x7fffffff;
        const unsigned long long m = __ballot(v < val);
        lo += __popcll(m);
    }
    return lo;
}

__global__ __launch_bounds__(256)
void word_pool_kernel(const float* __restrict__ hs,
                      const int* __restrict__ seg,
                      float* __restrict__ out,
                      int n_tokens, int H, int n_words) {
    const int wave = threadIdx.x >> 6;     // 0..3
    const int lane = threadIdx.x & 63;
    const int w = blockIdx.x * 4 + wave;
    if (w >= n_words) return;

    // Two independent 3-round wave-parallel searches (chains overlap).
    const int start = wave_lower_bound(seg, n_tokens, w, lane);
    const int end   = wave_lower_bound(seg, n_tokens, w + 1, lane);

    // H = 1024 = 64 lanes * 4 chunks * 4 floats.
    const int c0 = lane * 4;               // chunk j at column c0 + j*256

    float4 acc0 = make_float4(0.f, 0.f, 0.f, 0.f);
    float4 acc1 = acc0, acc2 = acc0, acc3 = acc0;

    for (int t = start; t < end; ++t) {
        const float* row = hs + (size_t)t * H + c0;
        const float4 v0 = *reinterpret_cast<const float4*>(row);
        const float4 v1 = *reinterpret_cast<const float4*>(row + 256);
        const float4 v2 = *reinterpret_cast<const float4*>(row + 512);
        const float4 v3 = *reinterpret_cast<const float4*>(row + 768);
        acc0.x += v0.x; acc0.y += v0.y; acc0.z += v0.z; acc0.w += v0.w;
        acc1.x += v1.x; acc1.y += v1.y; acc1.z += v1.z; acc1.w += v1.w;
        acc2.x += v2.x; acc2.y += v2.y; acc2.z += v2.z; acc2.w += v2.w;
        acc3.x += v3.x; acc3.y += v3.y; acc3.z += v3.z; acc3.w += v3.w;
    }

    const int cnt = end - start;
    const float inv = (cnt > 0) ? (1.0f / (float)cnt) : 0.0f;
    acc0.x *= inv; acc0.y *= inv; acc0.z *= inv; acc0.w *= inv;
    acc1.x *= inv; acc1.y *= inv; acc1.z *= inv; acc1.w *= inv;
    acc2.x *= inv; acc2.y *= inv; acc2.z *= inv; acc2.w *= inv;
    acc3.x *= inv; acc3.y *= inv; acc3.z *= inv; acc3.w *= inv;

    float* orow = out + (size_t)w * H + c0;
    *reinterpret_cast<float4*>(orow)       = acc0;
    *reinterpret_cast<float4*>(orow + 256) = acc1;
    *reinterpret_cast<float4*>(orow + 512) = acc2;
    *reinterpret_cast<float4*>(orow + 768) = acc3;
}

extern "C" void kernel_launch(void* const* d_in, const int* in_sizes, int n_in,
                              void* d_out, int out_size, void* d_ws, size_t ws_size,
                              hipStream_t stream) {
    const float* hs  = (const float*)d_in[0];   // [B*S, H] flattened
    const int*   seg = (const int*)d_in[1];     // [B*S], sorted
    float* out = (float*)d_out;

    const int n_tokens = in_sizes[1];              // B*S = 32768
    const int H        = in_sizes[0] / n_tokens;   // 1024
    const int n_words  = out_size / H;             // 8192

    dim3 grid((n_words + 3) / 4);
    dim3 block(256);
    word_pool_kernel<<<grid, block, 0, stream>>>(hs, seg, out, n_tokens, H, n_words);
}